// Round 5
// baseline (198.890 us; speedup 1.0000x reference)
//
#include <hip/hip_runtime.h>

constexpr int NNODES_C = 50000;
constexpr int D = 16;
constexpr int NT = 16;

// d_ws layout (bytes):
//   pk   : u32[NNODES*NT]  @ 0           (3,200,000 B)
//          low16 = #out-edges to type t, high16 = #in-edges from type t
//   tcnt : int[NT]         @ 3,200,000   (64 B)
//   tlist: int[NT*NNODES]  @ 3,200,064   (3,200,000 B)
constexpr size_t OFF_PK    = 0;
constexpr size_t OFF_TCNT  = 3200000;
constexpr size_t OFF_TLIST = 3200064;
constexpr size_t ZERO_BYTES = OFF_TLIST; // zero pk + tcnt each call

__global__ __launch_bounds__(256)
void edge_kernel(const int* __restrict__ ei,
                 const int* __restrict__ types,
                 unsigned int* __restrict__ pk,
                 int E) {
    const int i = (blockIdx.x * blockDim.x + threadIdx.x) * 4;
    if (i >= E) return;
    if (i + 3 < E) {
        const int4 s4 = *reinterpret_cast<const int4*>(ei + i);
        const int4 t4 = *reinterpret_cast<const int4*>(ei + E + i);
        const int ss[4] = {s4.x, s4.y, s4.z, s4.w};
        const int tt[4] = {t4.x, t4.y, t4.z, t4.w};
        #pragma unroll
        for (int k = 0; k < 4; ++k) {
            const int ts = types[ss[k]];
            const int td = types[tt[k]];
            atomicAdd(&pk[ss[k] * NT + td], 1u);        // out-count at src
            atomicAdd(&pk[tt[k] * NT + ts], 0x10000u);  // in-count at dst
        }
    } else {
        for (int e = i; e < E; ++e) {
            const int s = ei[e];
            const int t = ei[E + e];
            atomicAdd(&pk[s * NT + types[t]], 1u);
            atomicAdd(&pk[t * NT + types[s]], 0x10000u);
        }
    }
}

__global__ __launch_bounds__(256)
void list_kernel(const int* __restrict__ types,
                 int* __restrict__ tcnt,
                 int* __restrict__ tlist,
                 int N) {
    __shared__ int lcnt[NT];
    __shared__ int lbase[NT];
    if (threadIdx.x < NT) lcnt[threadIdx.x] = 0;
    __syncthreads();

    const int n = blockIdx.x * 256 + threadIdx.x;
    int ty = 0, lr = 0;
    const bool valid = (n < N);
    if (valid) {
        ty = types[n];
        lr = atomicAdd(&lcnt[ty], 1);        // LDS atomic: cheap
    }
    __syncthreads();

    if (threadIdx.x < NT)
        lbase[threadIdx.x] = atomicAdd(&tcnt[threadIdx.x], lcnt[threadIdx.x]);
    __syncthreads();

    if (valid)
        tlist[ty * NNODES_C + lbase[ty] + lr] = n;
}

// 4 threads per node: thread handles row group rg = tid&3 (rows rg*4..rg*4+3).
// Sum decomposes over row groups, so each thread contributes its own ss/dg.
__global__ __launch_bounds__(256)
void node_kernel(const float* __restrict__ reps,
                 const float* __restrict__ rmaps,
                 const unsigned int* __restrict__ pk,
                 const int* __restrict__ tcnt,
                 const int* __restrict__ tlist,
                 float* __restrict__ out,
                 int N) {
    const int ty  = blockIdx.y;                  // block-uniform type
    const int cnt = tcnt[ty];
    if (blockIdx.x * 64 >= cnt) return;          // whole-block (uniform) exit

    const int rg = threadIdx.x & 3;              // row group 0..3
    const int r0 = rg * 4;

    // wave-uniform R base: all lanes in the block share type ty
    const float* __restrict__ Rb = rmaps + (size_t)ty * NT * D * D;

    float part = 0.0f;
    for (int i = blockIdx.x * 64 + (threadIdx.x >> 2); i < cnt;
         i += gridDim.x * 64) {
        const int n = tlist[ty * NNODES_C + i];

        const uint4* prow = reinterpret_cast<const uint4*>(pk + (size_t)n * NT);
        const uint4 w0 = prow[0], w1 = prow[1], w2 = prow[2], w3 = prow[3];
        const unsigned int w[NT] = {w0.x, w0.y, w0.z, w0.w,
                                    w1.x, w1.y, w1.z, w1.w,
                                    w2.x, w2.y, w2.z, w2.w,
                                    w3.x, w3.y, w3.z, w3.w};
        int dg = 0;
        int carr[NT];
        #pragma unroll
        for (int t = 0; t < NT; ++t) {
            const int hi = (int)(w[t] >> 16);
            carr[t] = (int)(w[t] & 0xFFFFu) - hi;
            dg += hi;
        }
        if (dg <= 0) continue;

        float x[D];
        #pragma unroll
        for (int j = 0; j < D; ++j) x[j] = reps[j * N + n];  // 4 lanes same addr: broadcast

        float y[4] = {0.f, 0.f, 0.f, 0.f};

        #pragma unroll 1
        for (int t = 0; t < NT; ++t) {
            const float ct = (float)carr[t];
            const float* __restrict__ Rt = Rb + t * D * D;
            #pragma unroll
            for (int r = 0; r < 4; ++r) {
                const float4 ra = *reinterpret_cast<const float4*>(Rt + (r0 + r) * D);
                const float4 rb = *reinterpret_cast<const float4*>(Rt + (r0 + r) * D + 4);
                const float4 rc = *reinterpret_cast<const float4*>(Rt + (r0 + r) * D + 8);
                const float4 rd = *reinterpret_cast<const float4*>(Rt + (r0 + r) * D + 12);
                float s = 0.0f;
                s = fmaf(ra.x, x[0],  s); s = fmaf(ra.y, x[1],  s);
                s = fmaf(ra.z, x[2],  s); s = fmaf(ra.w, x[3],  s);
                s = fmaf(rb.x, x[4],  s); s = fmaf(rb.y, x[5],  s);
                s = fmaf(rb.z, x[6],  s); s = fmaf(rb.w, x[7],  s);
                s = fmaf(rc.x, x[8],  s); s = fmaf(rc.y, x[9],  s);
                s = fmaf(rc.z, x[10], s); s = fmaf(rc.w, x[11], s);
                s = fmaf(rd.x, x[12], s); s = fmaf(rd.y, x[13], s);
                s = fmaf(rd.z, x[14], s); s = fmaf(rd.w, x[15], s);
                y[r] = fmaf(ct, s, y[r]);
            }
        }
        float ss = 0.0f;
        #pragma unroll
        for (int r = 0; r < 4; ++r) ss = fmaf(y[r], y[r], ss);
        part += ss / (float)dg;
    }

    // block reduction -> single atomic
    #pragma unroll
    for (int off = 32; off > 0; off >>= 1)
        part += __shfl_down(part, off);
    __shared__ float wpart[4];
    const int lane = threadIdx.x & 63;
    const int wid  = threadIdx.x >> 6;
    if (lane == 0) wpart[wid] = part;
    __syncthreads();
    if (threadIdx.x == 0) {
        const float v = wpart[0] + wpart[1] + wpart[2] + wpart[3];
        if (v != 0.0f) atomicAdd(out, v);
    }
}

extern "C" void kernel_launch(void* const* d_in, const int* in_sizes, int n_in,
                              void* d_out, int out_size, void* d_ws, size_t ws_size,
                              hipStream_t stream) {
    const float* reps  = (const float*)d_in[0];   // [16, N]
    const float* rmaps = (const float*)d_in[1];   // [16,16,16,16]
    const int*   ei    = (const int*)d_in[2];     // [2, E]
    const int*   types = (const int*)d_in[3];     // [N]
    float* out = (float*)d_out;

    const int E = in_sizes[2] / 2;
    const int N = in_sizes[3];

    char* ws = (char*)d_ws;
    unsigned int* pk = (unsigned int*)(ws + OFF_PK);
    int* tcnt  = (int*)(ws + OFF_TCNT);
    int* tlist = (int*)(ws + OFF_TLIST);

    hipMemsetAsync(d_ws, 0, ZERO_BYTES, stream);
    hipMemsetAsync(d_out, 0, sizeof(float), stream);

    edge_kernel<<<(E / 4 + 255) / 256, 256, 0, stream>>>(ei, types, pk, E);
    list_kernel<<<(N + 255) / 256, 256, 0, stream>>>(types, tcnt, tlist, N);

    // 4 threads/node, 64 nodes/block. ~3125 nodes/type -> 49 working
    // x-blocks/type (784 total ~ 3 blocks/CU, 12 waves/CU). grid-stride
    // covers skew; empty tail blocks exit on first load.
    dim3 grid(64, NT);
    node_kernel<<<grid, 256, 0, stream>>>(reps, rmaps, pk, tcnt, tlist, out, N);
}

// Round 6
// 102.135 us; speedup vs baseline: 1.9473x; 1.9473x over previous
//
#include <hip/hip_runtime.h>

constexpr int NNODES_C = 50000;
constexpr int D = 16;
constexpr int NT = 16;

// d_ws layout (bytes):
//   pk   : u32[NNODES*NT]  @ 0           (3,200,000 B)
//          low16 = #out-edges to type t, high16 = #in-edges from type t
//   tcnt : int[NT]         @ 3,200,000   (64 B)
//   tlist: int[NT*NNODES]  @ 3,200,064   (3,200,000 B)
constexpr size_t OFF_PK    = 0;
constexpr size_t OFF_TCNT  = 3200000;
constexpr size_t OFF_TLIST = 3200064;
constexpr size_t ZERO_BYTES = OFF_TLIST; // zero pk + tcnt each call

__global__ __launch_bounds__(256)
void edge_kernel(const int* __restrict__ ei,
                 const int* __restrict__ types,
                 unsigned int* __restrict__ pk,
                 int E) {
    const int i = (blockIdx.x * blockDim.x + threadIdx.x) * 4;
    if (i >= E) return;
    if (i + 3 < E) {
        const int4 s4 = *reinterpret_cast<const int4*>(ei + i);
        const int4 t4 = *reinterpret_cast<const int4*>(ei + E + i);
        const int ss[4] = {s4.x, s4.y, s4.z, s4.w};
        const int tt[4] = {t4.x, t4.y, t4.z, t4.w};
        #pragma unroll
        for (int k = 0; k < 4; ++k) {
            const int ts = types[ss[k]];
            const int td = types[tt[k]];
            atomicAdd(&pk[ss[k] * NT + td], 1u);        // out-count at src
            atomicAdd(&pk[tt[k] * NT + ts], 0x10000u);  // in-count at dst
        }
    } else {
        for (int e = i; e < E; ++e) {
            const int s = ei[e];
            const int t = ei[E + e];
            atomicAdd(&pk[s * NT + types[t]], 1u);
            atomicAdd(&pk[t * NT + types[s]], 0x10000u);
        }
    }
}

__global__ __launch_bounds__(256)
void list_kernel(const int* __restrict__ types,
                 int* __restrict__ tcnt,
                 int* __restrict__ tlist,
                 int N) {
    __shared__ int lcnt[NT];
    __shared__ int lbase[NT];
    if (threadIdx.x < NT) lcnt[threadIdx.x] = 0;
    __syncthreads();

    const int n = blockIdx.x * 256 + threadIdx.x;
    int ty = 0, lr = 0;
    const bool valid = (n < N);
    if (valid) {
        ty = types[n];
        lr = atomicAdd(&lcnt[ty], 1);        // LDS atomic: cheap
    }
    __syncthreads();

    if (threadIdx.x < NT)
        lbase[threadIdx.x] = atomicAdd(&tcnt[threadIdx.x], lcnt[threadIdx.x]);
    __syncthreads();

    if (valid)
        tlist[ty * NNODES_C + lbase[ty] + lr] = n;
}

// Node kernel, v3 structure:
//  - block <-> type ty; R[ty] (16KB) loaded ONCE into registers:
//    lane l = (tg=l>>4, r=l&15) holds rows r of types tg*4..tg*4+3 (16 float4).
//  - nodes streamed in 64-node batches through LDS (x, c, invdeg).
//  - consume: wave w processes nodes w, w+4, ...: 64 FMA/lane (no redundancy),
//    2-step shfl_xor reduction over tg, lanes<16 accumulate y^2*invdeg.
__global__ __launch_bounds__(256)
void node_kernel(const float* __restrict__ reps,
                 const float* __restrict__ rmaps,
                 const unsigned int* __restrict__ pk,
                 const int* __restrict__ tcnt,
                 const int* __restrict__ tlist,
                 float* __restrict__ out,
                 int N) {
    const int ty  = blockIdx.y;                  // block-uniform type
    const int cnt = tcnt[ty];
    if ((int)(blockIdx.x * 64) >= cnt) return;   // whole-block uniform exit

    const int tid = threadIdx.x;
    const int w   = tid >> 6;                    // wave id 0..3
    const int l   = tid & 63;                    // lane
    const int tg  = l >> 4;                      // type group 0..3
    const int r   = l & 15;                      // output row 0..15

    // R fragment: R[ty][tg*4+jt][r][0..15], jt=0..3 -> 16 float4 in VGPRs
    float4 Rf[4][4];
    {
        const float* Rbase = rmaps + (((size_t)ty * NT + tg * 4) * D + r) * D;
        #pragma unroll
        for (int jt = 0; jt < 4; ++jt)
            #pragma unroll
            for (int q = 0; q < 4; ++q)
                Rf[jt][q] = *reinterpret_cast<const float4*>(Rbase + jt * D * D + q * 4);
    }

    __shared__ int   NI[64];
    __shared__ float X[64][16];     // node x vectors
    __shared__ float C[64][16];     // per-type net counts (float)
    __shared__ int   PD[64][4];     // partial in-degree sums
    __shared__ float IDG[64];       // 1/deg (0 if deg==0)

    float part = 0.0f;

    for (int base = blockIdx.x * 64; base < cnt; base += gridDim.x * 64) {
        const int nb = min(64, cnt - base);

        __syncthreads();            // protect LDS from previous consume
        if (tid < nb) NI[tid] = tlist[ty * NNODES_C + base + tid];
        __syncthreads();

        const int b = tid >> 2, q = tid & 3;
        if (b < nb) {
            const int n = NI[b];
            const uint4 pw = *reinterpret_cast<const uint4*>(pk + (size_t)n * NT + q * 4);
            const unsigned int ws4[4] = {pw.x, pw.y, pw.z, pw.w};
            int hsum = 0;
            #pragma unroll
            for (int j = 0; j < 4; ++j) {
                const int hi = (int)(ws4[j] >> 16);
                const int lo = (int)(ws4[j] & 0xFFFFu);
                C[b][q * 4 + j] = (float)(lo - hi);
                hsum += hi;
            }
            PD[b][q] = hsum;
            #pragma unroll
            for (int j = 0; j < 4; ++j)
                X[b][q * 4 + j] = reps[(q * 4 + j) * N + n];
        }
        __syncthreads();
        if (tid < nb) {
            const int dg = PD[tid][0] + PD[tid][1] + PD[tid][2] + PD[tid][3];
            IDG[tid] = (dg > 0) ? (1.0f / (float)dg) : 0.0f;
        }
        __syncthreads();

        // consume: wave w owns nodes w, w+4, ...
        for (int bb = w; bb < nb; bb += 4) {
            const float4 x0 = *reinterpret_cast<const float4*>(&X[bb][0]);
            const float4 x1 = *reinterpret_cast<const float4*>(&X[bb][4]);
            const float4 x2 = *reinterpret_cast<const float4*>(&X[bb][8]);
            const float4 x3 = *reinterpret_cast<const float4*>(&X[bb][12]);
            const float4 c4 = *reinterpret_cast<const float4*>(&C[bb][tg * 4]);
            const float idg = IDG[bb];
            const float ca[4] = {c4.x, c4.y, c4.z, c4.w};

            float y = 0.0f;
            #pragma unroll
            for (int jt = 0; jt < 4; ++jt) {
                float s = 0.0f;
                s = fmaf(Rf[jt][0].x, x0.x, s); s = fmaf(Rf[jt][0].y, x0.y, s);
                s = fmaf(Rf[jt][0].z, x0.z, s); s = fmaf(Rf[jt][0].w, x0.w, s);
                s = fmaf(Rf[jt][1].x, x1.x, s); s = fmaf(Rf[jt][1].y, x1.y, s);
                s = fmaf(Rf[jt][1].z, x1.z, s); s = fmaf(Rf[jt][1].w, x1.w, s);
                s = fmaf(Rf[jt][2].x, x2.x, s); s = fmaf(Rf[jt][2].y, x2.y, s);
                s = fmaf(Rf[jt][2].z, x2.z, s); s = fmaf(Rf[jt][2].w, x2.w, s);
                s = fmaf(Rf[jt][3].x, x3.x, s); s = fmaf(Rf[jt][3].y, x3.y, s);
                s = fmaf(Rf[jt][3].z, x3.z, s); s = fmaf(Rf[jt][3].w, x3.w, s);
                y = fmaf(ca[jt], s, y);
            }
            // reduce over tg (lane bits 4,5): butterfly
            y += __shfl_xor(y, 16);
            y += __shfl_xor(y, 32);
            if (l < 16) part = fmaf(y * y, idg, part);
        }
    }

    // block reduction -> single atomic
    #pragma unroll
    for (int off = 32; off > 0; off >>= 1)
        part += __shfl_down(part, off);
    __shared__ float wpart[4];
    const int lane = threadIdx.x & 63;
    const int wid  = threadIdx.x >> 6;
    if (lane == 0) wpart[wid] = part;
    __syncthreads();
    if (threadIdx.x == 0) {
        const float v = wpart[0] + wpart[1] + wpart[2] + wpart[3];
        if (v != 0.0f) atomicAdd(out, v);
    }
}

extern "C" void kernel_launch(void* const* d_in, const int* in_sizes, int n_in,
                              void* d_out, int out_size, void* d_ws, size_t ws_size,
                              hipStream_t stream) {
    const float* reps  = (const float*)d_in[0];   // [16, N]
    const float* rmaps = (const float*)d_in[1];   // [16,16,16,16]
    const int*   ei    = (const int*)d_in[2];     // [2, E]
    const int*   types = (const int*)d_in[3];     // [N]
    float* out = (float*)d_out;

    const int E = in_sizes[2] / 2;
    const int N = in_sizes[3];

    char* ws = (char*)d_ws;
    unsigned int* pk = (unsigned int*)(ws + OFF_PK);
    int* tcnt  = (int*)(ws + OFF_TCNT);
    int* tlist = (int*)(ws + OFF_TLIST);

    hipMemsetAsync(d_ws, 0, ZERO_BYTES, stream);
    hipMemsetAsync(d_out, 0, sizeof(float), stream);

    edge_kernel<<<(E / 4 + 255) / 256, 256, 0, stream>>>(ei, types, pk, E);
    list_kernel<<<(N + 255) / 256, 256, 0, stream>>>(types, tcnt, tlist, N);

    // ~3125 nodes/type -> 49 batches of 64; 52 x-blocks/type with grid-stride
    // covers skew. 832 blocks ~ 3.25/CU, 13 waves/CU.
    dim3 grid(52, NT);
    node_kernel<<<grid, 256, 0, stream>>>(reps, rmaps, pk, tcnt, tlist, out, N);
}